// Round 1
// baseline (7373.179 us; speedup 1.0000x reference)
//
#include <hip/hip_runtime.h>
#include <stdint.h>

#define BM 64
#define BN 64
#define BK 32

// C[M,N] = act(A[M,K] @ W[N,K]^T), fp32 row-major, fp64 chunked accumulation.
// Tiles: 64x64 per block (256 thr, 4x4 per thread), K-major LDS for ds_read_b128.
template<bool RELU>
__global__ __launch_bounds__(256)
void gemm_nt_f32(const float* __restrict__ A, const float* __restrict__ W,
                 float* __restrict__ C, int M, int N, int K) {
    __shared__ __align__(16) float As[BK][BM];
    __shared__ __align__(16) float Ws[BK][BN];
    const int bn = blockIdx.x, bm = blockIdx.y;
    const int m0 = bm * BM, n0 = bn * BN;
    const int t = threadIdx.x;
    const int tx = t & 15, ty = t >> 4;

    float  accf[4][4];
    double accd[4][4];
#pragma unroll
    for (int i = 0; i < 4; ++i)
#pragma unroll
        for (int j = 0; j < 4; ++j) { accf[i][j] = 0.f; accd[i][j] = 0.0; }

    for (int kt = 0; kt < K; kt += BK) {
        // stage 64x32 A-tile and 64x32 W-tile, transposed to K-major
#pragma unroll
        for (int it = 0; it < 2; ++it) {
            int s = t + it * 256;            // 0..511
            int row = s >> 3, kq = s & 7;    // 64 rows x 8 float4
            float4 va = *(const float4*)(A + (size_t)(m0 + row) * K + kt + kq * 4);
            As[kq*4+0][row] = va.x; As[kq*4+1][row] = va.y;
            As[kq*4+2][row] = va.z; As[kq*4+3][row] = va.w;
            float4 vw = *(const float4*)(W + (size_t)(n0 + row) * K + kt + kq * 4);
            Ws[kq*4+0][row] = vw.x; Ws[kq*4+1][row] = vw.y;
            Ws[kq*4+2][row] = vw.z; Ws[kq*4+3][row] = vw.w;
        }
        __syncthreads();
#pragma unroll 8
        for (int kk = 0; kk < BK; ++kk) {
            float4 a4 = *(const float4*)&As[kk][ty * 4];
            float4 b4 = *(const float4*)&Ws[kk][tx * 4];
            float ar[4] = {a4.x, a4.y, a4.z, a4.w};
            float br[4] = {b4.x, b4.y, b4.z, b4.w};
#pragma unroll
            for (int i = 0; i < 4; ++i)
#pragma unroll
                for (int j = 0; j < 4; ++j)
                    accf[i][j] = fmaf(ar[i], br[j], accf[i][j]);
        }
        __syncthreads();
        // fold fp32 chunk into fp64 accumulator (kills the fp32 random walk:
        // dot error ~1e-7 so the downstream argmax matches the reference)
#pragma unroll
        for (int i = 0; i < 4; ++i)
#pragma unroll
            for (int j = 0; j < 4; ++j) { accd[i][j] += (double)accf[i][j]; accf[i][j] = 0.f; }
    }
#pragma unroll
    for (int i = 0; i < 4; ++i) {
        float v0 = (float)accd[i][0], v1 = (float)accd[i][1];
        float v2 = (float)accd[i][2], v3 = (float)accd[i][3];
        if (RELU) {
            v0 = fmaxf(v0, 0.f); v1 = fmaxf(v1, 0.f);
            v2 = fmaxf(v2, 0.f); v3 = fmaxf(v3, 0.f);
        }
        float4 o; o.x = v0; o.y = v1; o.z = v2; o.w = v3;
        *(float4*)(C + (size_t)(m0 + ty*4 + i) * N + n0 + tx*4) = o;
    }
}

// k[row] = argmax(scores[row,:]) + 1, first-occurrence tie-break (matches jnp.argmax).
// One wave per row, 4 rows per block.
__global__ __launch_bounds__(256)
void row_argmax_k(const float* __restrict__ S, int* __restrict__ KV, int Q) {
    int row  = blockIdx.x * 4 + (threadIdx.x >> 6);
    int lane = threadIdx.x & 63;
    const float* s = S + (size_t)row * Q;
    float best = -3.4e38f; int bidx = 0;
    for (int j = lane; j < Q; j += 64) {
        float v = s[j];
        if (v > best) { best = v; bidx = j; }   // ascending j => first occurrence per lane
    }
#pragma unroll
    for (int m = 1; m < 64; m <<= 1) {
        float ov = __shfl_xor(best, m);
        int   oi = __shfl_xor(bidx, m);
        if (ov > best || (ov == best && oi < bidx)) { best = ov; bidx = oi; }
    }
    if (lane == 0) KV[row] = bidx + 1;
}

// mask[row,q] = (stable-descending-rank of x[row,q]) < k[row].
// Exact stable semantics via bitonic sort of key = (~orderable(x) << 32) | index.
__global__ __launch_bounds__(512)
void topk_mask(const float* __restrict__ X, const int* __restrict__ KV,
               float* __restrict__ Mout, int Q) {
    __shared__ unsigned long long key[1024];
    __shared__ float mrow[1024];
    const int row = blockIdx.x;
    const int t = threadIdx.x;
    const float* x = X + (size_t)row * Q;
    for (int p = t; p < Q; p += 512) {
        unsigned fb = __float_as_uint(x[p]);
        unsigned u  = (fb & 0x80000000u) ? ~fb : (fb | 0x80000000u); // ascending-order map
        key[p] = ((unsigned long long)(~u) << 32) | (unsigned)p;      // asc key = desc value, asc idx
    }
    __syncthreads();
    for (int ksz = 2; ksz <= 1024; ksz <<= 1) {
        for (int j = ksz >> 1; j > 0; j >>= 1) {
            int a = ((t & ~(j - 1)) << 1) | (t & (j - 1));
            int b = a + j;
            bool up = ((a & ksz) == 0);
            unsigned long long ka = key[a], kb = key[b];
            if ((ka > kb) == up) { key[a] = kb; key[b] = ka; }
            __syncthreads();
        }
    }
    const int kk = KV[row];
    for (int p = t; p < Q; p += 512) {
        int idx = (int)(key[p] & 0xFFFFFFFFu);
        mrow[idx] = (p < kk) ? 1.0f : 0.0f;
    }
    __syncthreads();
    for (int p = t; p < Q; p += 512)
        Mout[(size_t)row * Q + p] = mrow[p];
}

extern "C" void kernel_launch(void* const* d_in, const int* in_sizes, int n_in,
                              void* d_out, int out_size, void* d_ws, size_t ws_size,
                              hipStream_t stream) {
    const int B = 32768, Q = 1024, E = 1024;
    const float* x  = (const float*)d_in[0];
    const float* W1 = (const float*)d_in[1];   // [2Q, Q]
    const float* W2 = (const float*)d_in[2];   // [Q, 2Q]
    const float* W3 = (const float*)d_in[3];   // [Q, Q]
    const float* Wc = (const float*)d_in[4];   // [E, Q]
    float* out = (float*)d_out;

    // ws layout: [0, 256MiB) H1; after argmax, first half holds scores,
    // second half holds mask; k-values after 256MiB. d_out doubles as H2 scratch.
    float* H1   = (float*)d_ws;                            // B x 2Q
    float* H2   = out;                                     // B x Q (scratch in d_out)
    float* SC   = (float*)d_ws;                            // B x Q (reuses H1 1st half)
    float* MASK = (float*)d_ws + (size_t)B * Q;            // B x Q (reuses H1 2nd half)
    int*   KV   = (int*)((char*)d_ws + (size_t)B * 2 * Q * sizeof(float));

    dim3 blk(256);
    // h1 = relu(x @ W1^T)        [B, 2Q]
    gemm_nt_f32<true ><<<dim3(2*Q/BN, B/BM), blk, 0, stream>>>(x,  W1, H1, B, 2*Q, Q);
    // h2 = relu(h1 @ W2^T)       [B, Q]
    gemm_nt_f32<true ><<<dim3(Q/BN,   B/BM), blk, 0, stream>>>(H1, W2, H2, B, Q, 2*Q);
    // scores = h2 @ W3^T         [B, Q]
    gemm_nt_f32<false><<<dim3(Q/BN,   B/BM), blk, 0, stream>>>(H2, W3, SC, B, Q, Q);
    // k per row
    row_argmax_k<<<dim3(B/4), blk, 0, stream>>>(SC, KV, Q);
    // stable top-k mask on x
    topk_mask<<<dim3(B), dim3(512), 0, stream>>>(x, KV, MASK, Q);
    // out = mask @ Wc^T          [B, E]
    gemm_nt_f32<false><<<dim3(E/BN,   B/BM), blk, 0, stream>>>(MASK, Wc, out, B, E, Q);
}

// Round 2
// 4562.490 us; speedup vs baseline: 1.6160x; 1.6160x over previous
//
#include <hip/hip_runtime.h>
#include <stdint.h>

#define B_  32768
#define Q_  1024
#define E_  1024

typedef __attribute__((ext_vector_type(8))) short bf16x8;
typedef __attribute__((ext_vector_type(4))) float f32x4;

__device__ __forceinline__ f32x4 MFMA16(bf16x8 a, bf16x8 b, f32x4 c) {
    return __builtin_amdgcn_mfma_f32_16x16x32_bf16(a, b, c, 0, 0, 0);
}

__device__ __forceinline__ unsigned short f2bf(float v) {   // RNE fp32->bf16
    unsigned u = __float_as_uint(v);
    u += 0x7FFFu + ((u >> 16) & 1u);
    return (unsigned short)(u >> 16);
}
__device__ __forceinline__ float bf2f(unsigned short b) {
    return __uint_as_float(((unsigned)b) << 16);
}

// 16B-chunk index inside a 128x32-bf16 LDS tile, XOR-swizzled so that the
// MFMA fragment read (16 lanes = 16 consecutive rows, same koff) spreads
// across banks (2-way residual = free, m136).
__device__ __forceinline__ int chunk_of(int row, int koff) {
    return row * 4 + (koff ^ (row & 3));
}

// split fp32 16-elem row segment into bf16 hi/lo planes, store swizzled 16B chunks
template<int NPASS>
__device__ __forceinline__ void split_store(unsigned short* S0, unsigned short* S1,
                                            int rowX, int koffX, float4 a, float4 b) {
    int ch = chunk_of(rowX, koffX);
    float f[8] = {a.x, a.y, a.z, a.w, b.x, b.y, b.z, b.w};
    bf16x8 lo, hi;
#pragma unroll
    for (int j = 0; j < 8; ++j) {
        unsigned short c0 = f2bf(f[j]);
        lo[j] = (short)c0;
        hi[j] = (short)f2bf(f[j] - bf2f(c0));   // exact residual (Sterbenz)
    }
    *(bf16x8*)&S0[ch * 8] = lo;
    if constexpr (NPASS == 3) *(bf16x8*)&S1[ch * 8] = hi;
}

// C[M,N] = act(A @ W^T) via split-bf16 MFMA.
//   NPASS=3: acc = A0 B0 + A0 B1 + A1 B0   (fp32-grade, dropped a1b1 ~ 2^-16)
//   NPASS=1: acc = A0 B0                   (plain bf16)
// AF32:  A is fp32, reg-split-staged. else A = two bf16 planes via global_load_lds.
// W always fp32, reg-split-staged (weights are tiny / L2-resident).
// EMITP: emit bf16 hi/lo planes (for next layer); else fp32.
template<int NPASS, bool AF32, bool RELU, bool EMITP>
__global__ __launch_bounds__(256, 2)
void gemm3p(const void* __restrict__ Ap0, const void* __restrict__ Ap1,
            const float* __restrict__ Wf,
            void* __restrict__ Cp0, void* __restrict__ Cp1,
            int M, int N, int K) {
    __shared__ __align__(16) unsigned short A0s[128 * 32];
    __shared__ __align__(16) unsigned short B0s[128 * 32];
    __shared__ __align__(16) unsigned short A1s[(NPASS == 3) ? 128 * 32 : 8];
    __shared__ __align__(16) unsigned short B1s[(NPASS == 3) ? 128 * 32 : 8];

    const int t = threadIdx.x;
    const int wave = t >> 6, lane = t & 63;
    const int lanelo = lane & 15, kq = lane >> 4;
    const int wm = wave >> 1, wn = wave & 1;
    const int m0 = blockIdx.y * 128, n0 = blockIdx.x * 128;
    const int brow = t >> 1, bhalf = t & 1;   // staging: 128 rows x 2 halves of 16

    f32x4 acc[4][4];
#pragma unroll
    for (int i = 0; i < 4; ++i)
#pragma unroll
        for (int j = 0; j < 4; ++j) acc[i][j] = (f32x4){0.f, 0.f, 0.f, 0.f};

    for (int kt = 0; kt < K; kt += 32) {
        __syncthreads();   // prior compute done before LDS overwrite
        // ---- issue weight loads (fp32) ----
        const float* wp = Wf + (size_t)(n0 + brow) * K + kt + bhalf * 16;
        float4 v0 = *(const float4*)(wp + 0);
        float4 v1 = *(const float4*)(wp + 4);
        float4 v2 = *(const float4*)(wp + 8);
        float4 v3 = *(const float4*)(wp + 12);
        // ---- A staging ----
        if constexpr (AF32) {
            const float* ap = (const float*)Ap0 + (size_t)(m0 + brow) * K + kt + bhalf * 16;
            float4 u0 = *(const float4*)(ap + 0);
            float4 u1 = *(const float4*)(ap + 4);
            float4 u2 = *(const float4*)(ap + 8);
            float4 u3 = *(const float4*)(ap + 12);
            split_store<NPASS>(A0s, A1s, brow, bhalf * 2 + 0, u0, u1);
            split_store<NPASS>(A0s, A1s, brow, bhalf * 2 + 1, u2, u3);
        } else {
            // async global->LDS, pre-swizzled source, linear dest (rule #21)
#pragma unroll
            for (int g = 0; g < 2; ++g) {
                int c = (g * 4 + wave) * 64 + lane;
                int row = c >> 2;
                int koff = (c & 3) ^ (row & 3);
                const unsigned short* s0 =
                    (const unsigned short*)Ap0 + (size_t)(m0 + row) * K + kt + koff * 8;
                __builtin_amdgcn_global_load_lds(
                    (const __attribute__((address_space(1))) void*)s0,
                    (__attribute__((address_space(3))) void*)&A0s[(size_t)(g * 4 + wave) * 64 * 8],
                    16, 0, 0);
                if constexpr (NPASS == 3) {
                    const unsigned short* s1 =
                        (const unsigned short*)Ap1 + (size_t)(m0 + row) * K + kt + koff * 8;
                    __builtin_amdgcn_global_load_lds(
                        (const __attribute__((address_space(1))) void*)s1,
                        (__attribute__((address_space(3))) void*)&A1s[(size_t)(g * 4 + wave) * 64 * 8],
                        16, 0, 0);
                }
            }
        }
        // ---- split + write weights ----
        split_store<NPASS>(B0s, B1s, brow, bhalf * 2 + 0, v0, v1);
        split_store<NPASS>(B0s, B1s, brow, bhalf * 2 + 1, v2, v3);
        __syncthreads();   // drains vmcnt (gload_lds) + lgkm (ds_write)

        // ---- fragments + MFMA ----
        bf16x8 a0[4], a1[4];
#pragma unroll
        for (int mf = 0; mf < 4; ++mf) {
            int ar = wm * 64 + mf * 16 + lanelo;
            int ac = chunk_of(ar, kq);
            a0[mf] = *(const bf16x8*)&A0s[ac * 8];
            if constexpr (NPASS == 3) a1[mf] = *(const bf16x8*)&A1s[ac * 8];
        }
#pragma unroll
        for (int nf = 0; nf < 4; ++nf) {
            int br = wn * 64 + nf * 16 + lanelo;
            int bc = chunk_of(br, kq);
            bf16x8 vb0 = *(const bf16x8*)&B0s[bc * 8];
#pragma unroll
            for (int mf = 0; mf < 4; ++mf) acc[mf][nf] = MFMA16(a0[mf], vb0, acc[mf][nf]);
            if constexpr (NPASS == 3) {
                bf16x8 vb1 = *(const bf16x8*)&B1s[bc * 8];
#pragma unroll
                for (int mf = 0; mf < 4; ++mf) acc[mf][nf] = MFMA16(a0[mf], vb1, acc[mf][nf]);
#pragma unroll
                for (int mf = 0; mf < 4; ++mf) acc[mf][nf] = MFMA16(a1[mf], vb0, acc[mf][nf]);
            }
        }
    }

    // ---- epilogue (C/D layout: col=lane&15, row=(lane>>4)*4+reg — m89/m91) ----
#pragma unroll
    for (int mf = 0; mf < 4; ++mf)
#pragma unroll
        for (int nf = 0; nf < 4; ++nf)
#pragma unroll
            for (int r = 0; r < 4; ++r) {
                int row = m0 + wm * 64 + mf * 16 + kq * 4 + r;
                int col = n0 + wn * 64 + nf * 16 + lanelo;
                float v = acc[mf][nf][r];
                if constexpr (RELU) v = fmaxf(v, 0.f);
                if constexpr (EMITP) {
                    unsigned short c0 = f2bf(v);
                    ((unsigned short*)Cp0)[(size_t)row * N + col] = c0;
                    ((unsigned short*)Cp1)[(size_t)row * N + col] = f2bf(v - bf2f(c0));
                } else {
                    ((float*)Cp0)[(size_t)row * N + col] = v;
                }
            }
}

// k[row] = argmax+1 (first-occurrence); flag rows whose top-2 gap < theta
__global__ __launch_bounds__(256)
void row_argmax_flag(const float* __restrict__ S, int* __restrict__ KV,
                     int* __restrict__ flags, int* __restrict__ cnt) {
    int row = blockIdx.x * 4 + (threadIdx.x >> 6);
    int lane = threadIdx.x & 63;
    const float* s = S + (size_t)row * Q_;
    float b1 = -3.4e38f, b2 = -3.4e38f; int i1 = 0;
    for (int j = lane; j < Q_; j += 64) {
        float v = s[j];
        if (v > b1) { b2 = b1; b1 = v; i1 = j; }
        else if (v > b2) b2 = v;
    }
#pragma unroll
    for (int m = 1; m < 64; m <<= 1) {
        float o1 = __shfl_xor(b1, m);
        int   oi = __shfl_xor(i1, m);
        float o2 = __shfl_xor(b2, m);
        if (o1 > b1 || (o1 == b1 && oi < i1)) {
            b2 = fmaxf(b1, o2); b1 = o1; i1 = oi;
        } else {
            b2 = fmaxf(b2, fmaxf(o1 == b1 ? -3.4e38f : o1, o2) >= b1 ? o2 : fmaxf(b2, o1));
        }
        // simpler correct merge: recompute below
    }
    // NOTE: the branch above got convoluted; redo reduction cleanly
    // (recompute from scratch to be safe)
    b1 = -3.4e38f; b2 = -3.4e38f; i1 = 0;
    for (int j = lane; j < Q_; j += 64) {
        float v = s[j];
        if (v > b1) { b2 = b1; b1 = v; i1 = j; }
        else if (v > b2) b2 = v;
    }
#pragma unroll
    for (int m = 1; m < 64; m <<= 1) {
        float o1 = __shfl_xor(b1, m);
        int   oi = __shfl_xor(i1, m);
        float o2 = __shfl_xor(b2, m);
        if (o1 > b1 || (o1 == b1 && oi < i1)) {
            b2 = fmaxf(b1, o2);
            b1 = o1; i1 = oi;
        } else {
            b2 = fmaxf(b2, o1);
        }
    }
    if (lane == 0) {
        KV[row] = i1 + 1;
        if (b1 - b2 < 1e-3f) { int p = atomicAdd(cnt, 1); flags[p] = row; }
    }
}

// exact (fp64-accum) re-evaluation of the selector MLP for flagged rows
__global__ __launch_bounds__(256)
void rescore(const float* __restrict__ X, const float* __restrict__ W1,
             const float* __restrict__ W2, const float* __restrict__ W3,
             const int* __restrict__ flags, const int* __restrict__ cnt,
             int* __restrict__ KV) {
    __shared__ float xr[Q_];
    __shared__ float h1[2 * Q_];
    __shared__ float h2[Q_];
    __shared__ float rv[4];
    __shared__ int   ri[4];
    const int t = threadIdx.x, lane = t & 63, wv = t >> 6;
    const int n = *cnt;
    for (int it = blockIdx.x; it < n; it += gridDim.x) {
        const int row = flags[it];
        __syncthreads();
        for (int p = t; p < Q_; p += 256) xr[p] = X[(size_t)row * Q_ + p];
        __syncthreads();
        for (int c = t; c < 2 * Q_; c += 256) {
            const float* w = W1 + (size_t)c * Q_;
            double a = 0.0;
            for (int k = 0; k < Q_; ++k) a += (double)xr[k] * (double)w[k];
            h1[c] = fmaxf((float)a, 0.f);   // round to fp32 like the reference
        }
        __syncthreads();
        for (int c = t; c < Q_; c += 256) {
            const float* w = W2 + (size_t)c * 2 * Q_;
            double a = 0.0;
            for (int k = 0; k < 2 * Q_; ++k) a += (double)h1[k] * (double)w[k];
            h2[c] = fmaxf((float)a, 0.f);
        }
        __syncthreads();
        float best = -3.4e38f; int bi = 0;
        for (int c = t; c < Q_; c += 256) {
            const float* w = W3 + (size_t)c * Q_;
            double a = 0.0;
            for (int k = 0; k < Q_; ++k) a += (double)h2[k] * (double)w[k];
            float sc = (float)a;
            if (sc > best) { best = sc; bi = c; }
        }
#pragma unroll
        for (int m = 1; m < 64; m <<= 1) {
            float ov = __shfl_xor(best, m); int oi = __shfl_xor(bi, m);
            if (ov > best || (ov == best && oi < bi)) { best = ov; bi = oi; }
        }
        if (lane == 0) { rv[wv] = best; ri[wv] = bi; }
        __syncthreads();
        if (t == 0) {
            float bb = rv[0]; int bj = ri[0];
            for (int w2 = 1; w2 < 4; ++w2)
                if (rv[w2] > bb || (rv[w2] == bb && ri[w2] < bj)) { bb = rv[w2]; bj = ri[w2]; }
            KV[row] = bj + 1;
        }
        __syncthreads();
    }
}

// stable-descending-rank top-k mask (bitonic on (~orderable(x), idx)), bf16 out
__global__ __launch_bounds__(512)
void topk_mask(const float* __restrict__ X, const int* __restrict__ KV,
               unsigned short* __restrict__ Mout) {
    __shared__ unsigned long long key[1024];
    __shared__ unsigned short mrow[1024];
    const int row = blockIdx.x;
    const int t = threadIdx.x;
    const float* x = X + (size_t)row * Q_;
    for (int p = t; p < Q_; p += 512) {
        unsigned fb = __float_as_uint(x[p]);
        unsigned u  = (fb & 0x80000000u) ? ~fb : (fb | 0x80000000u);
        key[p] = ((unsigned long long)(~u) << 32) | (unsigned)p;
    }
    __syncthreads();
    for (int ksz = 2; ksz <= 1024; ksz <<= 1) {
        for (int j = ksz >> 1; j > 0; j >>= 1) {
            int a = ((t & ~(j - 1)) << 1) | (t & (j - 1));
            int b = a + j;
            bool up = ((a & ksz) == 0);
            unsigned long long ka = key[a], kb = key[b];
            if ((ka > kb) == up) { key[a] = kb; key[b] = ka; }
            __syncthreads();
        }
    }
    const int kk = KV[row];
    for (int p = t; p < Q_; p += 512) {
        int idx = (int)(key[p] & 0xFFFFFFFFu);
        mrow[idx] = (p < kk) ? (unsigned short)0x3F80 : (unsigned short)0;
    }
    __syncthreads();
    for (int p = t; p < Q_; p += 512)
        Mout[(size_t)row * Q_ + p] = mrow[p];
}

extern "C" void kernel_launch(void* const* d_in, const int* in_sizes, int n_in,
                              void* d_out, int out_size, void* d_ws, size_t ws_size,
                              hipStream_t stream) {
    const float* x  = (const float*)d_in[0];
    const float* W1 = (const float*)d_in[1];   // [2Q, Q]
    const float* W2 = (const float*)d_in[2];   // [Q, 2Q]
    const float* W3 = (const float*)d_in[3];   // [Q, Q]
    const float* Wc = (const float*)d_in[4];   // [E, Q]
    float* out = (float*)d_out;

    char* ws = (char*)d_ws;
    unsigned short* H1_0 = (unsigned short*)ws;                         // [B,2Q] bf16 hi (128MB)
    unsigned short* H1_1 = (unsigned short*)(ws + ((size_t)128 << 20)); // [B,2Q] bf16 lo (128MB)
    float*          SC   = (float*)ws;                                  // scores, aliases H1_0 (dead)
    unsigned short* MASKB= (unsigned short*)(ws + ((size_t)128 << 20)); // mask bf16, aliases H1_1 (dead)
    int* KV    = (int*)(ws + ((size_t)256 << 20));
    int* FLAGS = KV + B_;
    int* CNT   = FLAGS + B_;
    unsigned short* H2_0 = (unsigned short*)d_out;                      // [B,Q] bf16 hi (64MB)
    unsigned short* H2_1 = (unsigned short*)d_out + (size_t)B_ * Q_;    // [B,Q] bf16 lo (64MB)

    hipMemsetAsync(CNT, 0, sizeof(int), stream);
    dim3 blk(256);
    // h1 = relu(x @ W1^T): A fp32 reg-split, emit planes
    gemm3p<3, true,  true,  true ><<<dim3(2 * Q_ / 128, B_ / 128), blk, 0, stream>>>(
        x, nullptr, W1, H1_0, H1_1, B_, 2 * Q_, Q_);
    // h2 = relu(h1 @ W2^T): A planes (gload_lds), emit planes into d_out (scratch)
    gemm3p<3, false, true,  true ><<<dim3(Q_ / 128, B_ / 128), blk, 0, stream>>>(
        H1_0, H1_1, W2, H2_0, H2_1, B_, Q_, 2 * Q_);
    // scores = h2 @ W3^T: fp32 out (overwrites dead H1_0 region)
    gemm3p<3, false, false, false><<<dim3(Q_ / 128, B_ / 128), blk, 0, stream>>>(
        H2_0, H2_1, W3, SC, nullptr, B_, Q_, Q_);
    row_argmax_flag<<<dim3(B_ / 4), blk, 0, stream>>>(SC, KV, FLAGS, CNT);
    rescore<<<dim3(64), blk, 0, stream>>>(x, W1, W2, W3, FLAGS, CNT, KV);
    topk_mask<<<dim3(B_), dim3(512), 0, stream>>>(x, KV, MASKB);
    // out = mask @ Wc^T: plain bf16 MFMA (overwrites dead H2 planes)
    gemm3p<1, false, false, false><<<dim3(E_ / 128, B_ / 128), blk, 0, stream>>>(
        MASKB, nullptr, Wc, out, nullptr, B_, E_, Q_);
}

// Round 3
// 2716.321 us; speedup vs baseline: 2.7144x; 1.6797x over previous
//
#include <hip/hip_runtime.h>
#include <stdint.h>

#define B_  32768
#define Q_  1024
#define E_  1024
#define CAPF 16384   // max flagged rows the rescore scratch layout supports

typedef __attribute__((ext_vector_type(8))) short bf16x8;
typedef __attribute__((ext_vector_type(4))) float f32x4;

__device__ __forceinline__ f32x4 MFMA16(bf16x8 a, bf16x8 b, f32x4 c) {
    return __builtin_amdgcn_mfma_f32_16x16x32_bf16(a, b, c, 0, 0, 0);
}

__device__ __forceinline__ unsigned short f2bf(float v) {   // RNE fp32->bf16
    unsigned u = __float_as_uint(v);
    u += 0x7FFFu + ((u >> 16) & 1u);
    return (unsigned short)(u >> 16);
}
__device__ __forceinline__ float bf2f(unsigned short b) {
    return __uint_as_float(((unsigned)b) << 16);
}

// 16B-chunk index inside a 128x32-bf16 LDS tile, XOR-swizzled so the MFMA
// fragment read (16 lanes = 16 consecutive rows, same koff) spreads banks.
__device__ __forceinline__ int chunk_of(int row, int koff) {
    return row * 4 + (koff ^ (row & 3));
}

template<int NPASS>
__device__ __forceinline__ void split_store(unsigned short* S0, unsigned short* S1,
                                            int rowX, int koffX, float4 a, float4 b) {
    int ch = chunk_of(rowX, koffX);
    float f[8] = {a.x, a.y, a.z, a.w, b.x, b.y, b.z, b.w};
    bf16x8 lo, hi;
#pragma unroll
    for (int j = 0; j < 8; ++j) {
        unsigned short c0 = f2bf(f[j]);
        lo[j] = (short)c0;
        hi[j] = (short)f2bf(f[j] - bf2f(c0));   // exact residual (Sterbenz)
    }
    *(bf16x8*)&S0[ch * 8] = lo;
    if constexpr (NPASS == 3) *(bf16x8*)&S1[ch * 8] = hi;
}

// C[M,N] = act(A @ W^T) via split-bf16 MFMA.
//   NPASS=3: acc = A0B0 + A0B1 + A1B0 (fp32-grade);  NPASS=1: plain bf16.
template<int NPASS, bool AF32, bool RELU, bool EMITP>
__global__ __launch_bounds__(256, 2)
void gemm3p(const void* __restrict__ Ap0, const void* __restrict__ Ap1,
            const float* __restrict__ Wf,
            void* __restrict__ Cp0, void* __restrict__ Cp1,
            int M, int N, int K) {
    __shared__ __align__(16) unsigned short A0s[128 * 32];
    __shared__ __align__(16) unsigned short B0s[128 * 32];
    __shared__ __align__(16) unsigned short A1s[(NPASS == 3) ? 128 * 32 : 8];
    __shared__ __align__(16) unsigned short B1s[(NPASS == 3) ? 128 * 32 : 8];

    const int t = threadIdx.x;
    const int wave = t >> 6, lane = t & 63;
    const int lanelo = lane & 15, kq = lane >> 4;
    const int wm = wave >> 1, wn = wave & 1;
    const int m0 = blockIdx.y * 128, n0 = blockIdx.x * 128;
    const int brow = t >> 1, bhalf = t & 1;

    f32x4 acc[4][4];
#pragma unroll
    for (int i = 0; i < 4; ++i)
#pragma unroll
        for (int j = 0; j < 4; ++j) acc[i][j] = (f32x4){0.f, 0.f, 0.f, 0.f};

    for (int kt = 0; kt < K; kt += 32) {
        __syncthreads();
        const float* wp = Wf + (size_t)(n0 + brow) * K + kt + bhalf * 16;
        float4 v0 = *(const float4*)(wp + 0);
        float4 v1 = *(const float4*)(wp + 4);
        float4 v2 = *(const float4*)(wp + 8);
        float4 v3 = *(const float4*)(wp + 12);
        if constexpr (AF32) {
            const float* ap = (const float*)Ap0 + (size_t)(m0 + brow) * K + kt + bhalf * 16;
            float4 u0 = *(const float4*)(ap + 0);
            float4 u1 = *(const float4*)(ap + 4);
            float4 u2 = *(const float4*)(ap + 8);
            float4 u3 = *(const float4*)(ap + 12);
            split_store<NPASS>(A0s, A1s, brow, bhalf * 2 + 0, u0, u1);
            split_store<NPASS>(A0s, A1s, brow, bhalf * 2 + 1, u2, u3);
        } else {
#pragma unroll
            for (int g = 0; g < 2; ++g) {
                int c = (g * 4 + wave) * 64 + lane;
                int row = c >> 2;
                int koff = (c & 3) ^ (row & 3);
                const unsigned short* s0 =
                    (const unsigned short*)Ap0 + (size_t)(m0 + row) * K + kt + koff * 8;
                __builtin_amdgcn_global_load_lds(
                    (const __attribute__((address_space(1))) void*)s0,
                    (__attribute__((address_space(3))) void*)&A0s[(size_t)(g * 4 + wave) * 64 * 8],
                    16, 0, 0);
                if constexpr (NPASS == 3) {
                    const unsigned short* s1 =
                        (const unsigned short*)Ap1 + (size_t)(m0 + row) * K + kt + koff * 8;
                    __builtin_amdgcn_global_load_lds(
                        (const __attribute__((address_space(1))) void*)s1,
                        (__attribute__((address_space(3))) void*)&A1s[(size_t)(g * 4 + wave) * 64 * 8],
                        16, 0, 0);
                }
            }
        }
        split_store<NPASS>(B0s, B1s, brow, bhalf * 2 + 0, v0, v1);
        split_store<NPASS>(B0s, B1s, brow, bhalf * 2 + 1, v2, v3);
        __syncthreads();

        bf16x8 a0[4], a1[4];
#pragma unroll
        for (int mf = 0; mf < 4; ++mf) {
            int ar = wm * 64 + mf * 16 + lanelo;
            int ac = chunk_of(ar, kq);
            a0[mf] = *(const bf16x8*)&A0s[ac * 8];
            if constexpr (NPASS == 3) a1[mf] = *(const bf16x8*)&A1s[ac * 8];
        }
#pragma unroll
        for (int nf = 0; nf < 4; ++nf) {
            int br = wn * 64 + nf * 16 + lanelo;
            int bc = chunk_of(br, kq);
            bf16x8 vb0 = *(const bf16x8*)&B0s[bc * 8];
#pragma unroll
            for (int mf = 0; mf < 4; ++mf) acc[mf][nf] = MFMA16(a0[mf], vb0, acc[mf][nf]);
            if constexpr (NPASS == 3) {
                bf16x8 vb1 = *(const bf16x8*)&B1s[bc * 8];
#pragma unroll
                for (int mf = 0; mf < 4; ++mf) acc[mf][nf] = MFMA16(a0[mf], vb1, acc[mf][nf]);
#pragma unroll
                for (int mf = 0; mf < 4; ++mf) acc[mf][nf] = MFMA16(a1[mf], vb0, acc[mf][nf]);
            }
        }
    }

    // C/D layout: col=lane&15, row=(lane>>4)*4+reg (m89/m91)
#pragma unroll
    for (int mf = 0; mf < 4; ++mf)
#pragma unroll
        for (int nf = 0; nf < 4; ++nf)
#pragma unroll
            for (int r = 0; r < 4; ++r) {
                int row = m0 + wm * 64 + mf * 16 + kq * 4 + r;
                int col = n0 + wn * 64 + nf * 16 + lanelo;
                float v = acc[mf][nf][r];
                if constexpr (RELU) v = fmaxf(v, 0.f);
                if constexpr (EMITP) {
                    unsigned short c0 = f2bf(v);
                    ((unsigned short*)Cp0)[(size_t)row * N + col] = c0;
                    ((unsigned short*)Cp1)[(size_t)row * N + col] = f2bf(v - bf2f(c0));
                } else {
                    ((float*)Cp0)[(size_t)row * N + col] = v;
                }
            }
}

// k[row] = argmax+1 (first occurrence); flag rows whose top-2 gap < theta
__global__ __launch_bounds__(256)
void row_argmax_flag(const float* __restrict__ S, int* __restrict__ KV,
                     int* __restrict__ flags, int* __restrict__ cnt) {
    int row = blockIdx.x * 4 + (threadIdx.x >> 6);
    int lane = threadIdx.x & 63;
    const float* s = S + (size_t)row * Q_;
    float b1 = -3.4e38f, b2 = -3.4e38f; int i1 = 0;
    for (int j = lane; j < Q_; j += 64) {
        float v = s[j];
        if (v > b1) { b2 = b1; b1 = v; i1 = j; }
        else if (v > b2) b2 = v;
    }
#pragma unroll
    for (int m = 1; m < 64; m <<= 1) {
        float o1 = __shfl_xor(b1, m);
        int   oi = __shfl_xor(i1, m);
        float o2 = __shfl_xor(b2, m);
        if (o1 > b1 || (o1 == b1 && oi < i1)) {
            b2 = fmaxf(b1, o2);        // old max becomes second-best candidate
            b1 = o1; i1 = oi;
        } else {
            b2 = fmaxf(b2, o1);        // o1 <= b1 (or dup): second-best candidate
        }
    }
    if (lane == 0) {
        KV[row] = i1 + 1;
        if (b1 - b2 < 1e-3f) { int p = atomicAdd(cnt, 1); flags[p] = row; }
    }
}

// ---- parallel coalesced rescore: one wave per output column, fp64 accum ----
// work item = (flagged-row it, 16-column chunk); 4 waves x 4 cols per block.
template<bool IN_BY_FLAG, bool RELU>
__global__ __launch_bounds__(256)
void rescore_gemm(const float* __restrict__ IN, const float* __restrict__ W,
                  float* __restrict__ OUT, const int* __restrict__ flags,
                  const int* __restrict__ cnt, int K, int N) {
    __shared__ float xr[2 * Q_];
    const int t = threadIdx.x, lane = t & 63, wv = t >> 6;
    const int n = min(*cnt, CAPF);
    const int chunks = N >> 4;
    for (int w = blockIdx.x; w < n * chunks; w += gridDim.x) {
        const int it = w / chunks, ch = w - it * chunks;
        const float* rp = IN_BY_FLAG ? IN + (size_t)flags[it] * K
                                     : IN + (size_t)it * K;
        __syncthreads();
        for (int p = t; p < K; p += 256) xr[p] = rp[p];
        __syncthreads();
#pragma unroll
        for (int jj = 0; jj < 4; ++jj) {
            const int col = ch * 16 + wv * 4 + jj;
            const float* wr = W + (size_t)col * K;
            double a = 0.0;
            for (int k = lane; k < K; k += 64)
                a += (double)xr[k] * (double)wr[k];   // coalesced weight reads
#pragma unroll
            for (int m = 1; m < 64; m <<= 1) a += __shfl_xor(a, m);
            if (lane == 0) {
                float v = (float)a;                    // round like the fp32 ref
                if (RELU) v = fmaxf(v, 0.f);
                OUT[(size_t)it * N + col] = v;
            }
        }
    }
}

// final exact argmax over rescored score rows, first-occurrence tie-break
__global__ __launch_bounds__(256)
void rescore_argmax(const float* __restrict__ SCF, const int* __restrict__ flags,
                    const int* __restrict__ cnt, int* __restrict__ KV) {
    const int lane = threadIdx.x & 63, wv = threadIdx.x >> 6;
    const int n = min(*cnt, CAPF);
    for (int it = blockIdx.x * 4 + wv; it < n; it += gridDim.x * 4) {
        const float* s = SCF + (size_t)it * Q_;
        float best = -3.4e38f; int bi = 0;
        for (int j = lane; j < Q_; j += 64) {
            float v = s[j];
            if (v > best) { best = v; bi = j; }
        }
#pragma unroll
        for (int m = 1; m < 64; m <<= 1) {
            float ov = __shfl_xor(best, m); int oi = __shfl_xor(bi, m);
            if (ov > best || (ov == best && oi < bi)) { best = ov; bi = oi; }
        }
        if (lane == 0) KV[flags[it]] = bi + 1;
    }
}

// stable-descending-rank top-k mask (bitonic on (~orderable(x), idx)), bf16 out
__global__ __launch_bounds__(512)
void topk_mask(const float* __restrict__ X, const int* __restrict__ KV,
               unsigned short* __restrict__ Mout) {
    __shared__ unsigned long long key[1024];
    __shared__ unsigned short mrow[1024];
    const int row = blockIdx.x;
    const int t = threadIdx.x;
    const float* x = X + (size_t)row * Q_;
    for (int p = t; p < Q_; p += 512) {
        unsigned fb = __float_as_uint(x[p]);
        unsigned u  = (fb & 0x80000000u) ? ~fb : (fb | 0x80000000u);
        key[p] = ((unsigned long long)(~u) << 32) | (unsigned)p;
    }
    __syncthreads();
    for (int ksz = 2; ksz <= 1024; ksz <<= 1) {
        for (int j = ksz >> 1; j > 0; j >>= 1) {
            int a = ((t & ~(j - 1)) << 1) | (t & (j - 1));
            int b = a + j;
            bool up = ((a & ksz) == 0);
            unsigned long long ka = key[a], kb = key[b];
            if ((ka > kb) == up) { key[a] = kb; key[b] = ka; }
            __syncthreads();
        }
    }
    const int kk = KV[row];
    for (int p = t; p < Q_; p += 512) {
        int idx = (int)(key[p] & 0xFFFFFFFFu);
        mrow[idx] = (p < kk) ? (unsigned short)0x3F80 : (unsigned short)0;
    }
    __syncthreads();
    for (int p = t; p < Q_; p += 512)
        Mout[(size_t)row * Q_ + p] = mrow[p];
}

extern "C" void kernel_launch(void* const* d_in, const int* in_sizes, int n_in,
                              void* d_out, int out_size, void* d_ws, size_t ws_size,
                              hipStream_t stream) {
    const float* x  = (const float*)d_in[0];
    const float* W1 = (const float*)d_in[1];   // [2Q, Q]
    const float* W2 = (const float*)d_in[2];   // [Q, 2Q]
    const float* W3 = (const float*)d_in[3];   // [Q, Q]
    const float* Wc = (const float*)d_in[4];   // [E, Q]
    float* out = (float*)d_out;

    char* ws = (char*)d_ws;
    unsigned short* H1_0 = (unsigned short*)ws;                         // [B,2Q] bf16 hi (128MB)
    unsigned short* H1_1 = (unsigned short*)(ws + ((size_t)128 << 20)); // [B,2Q] bf16 lo (128MB)
    float*          SC   = (float*)ws;                                  // scores (aliases H1_0, dead)
    unsigned short* MASKB= (unsigned short*)(ws + ((size_t)128 << 20)); // mask bf16 (aliases H1_1)
    int* KV    = (int*)(ws + ((size_t)256 << 20));
    int* FLAGS = KV + B_;
    int* CNT   = FLAGS + B_;
    unsigned short* H2_0 = (unsigned short*)d_out;                      // [B,Q] bf16 hi
    unsigned short* H2_1 = (unsigned short*)d_out + (size_t)B_ * Q_;    // [B,Q] bf16 lo
    // rescore scratch: SC region is dead after row_argmax_flag; MASKB region
    // is written only later by topk_mask. All stream-ordered.
    float* H1F = (float*)ws;                                            // [n,2Q] fp32
    float* H2F = (float*)(ws + ((size_t)128 << 20));                    // [n,Q]
    float* SCF = (float*)(ws + ((size_t)192 << 20));                    // [n,Q]

    hipMemsetAsync(CNT, 0, sizeof(int), stream);
    dim3 blk(256);
    // h1 = relu(x @ W1^T)
    gemm3p<3, true,  true,  true ><<<dim3(2 * Q_ / 128, B_ / 128), blk, 0, stream>>>(
        x, nullptr, W1, H1_0, H1_1, B_, 2 * Q_, Q_);
    // h2 = relu(h1 @ W2^T) -> planes in d_out scratch
    gemm3p<3, false, true,  true ><<<dim3(Q_ / 128, B_ / 128), blk, 0, stream>>>(
        H1_0, H1_1, W2, H2_0, H2_1, B_, Q_, 2 * Q_);
    // scores = h2 @ W3^T
    gemm3p<3, false, false, false><<<dim3(Q_ / 128, B_ / 128), blk, 0, stream>>>(
        H2_0, H2_1, W3, SC, nullptr, B_, Q_, Q_);
    row_argmax_flag<<<dim3(B_ / 4), blk, 0, stream>>>(SC, KV, FLAGS, CNT);
    // exact rescore of flagged rows (coalesced, whole-GPU parallel)
    rescore_gemm<true,  true ><<<dim3(2048), blk, 0, stream>>>(x,   W1, H1F, FLAGS, CNT, Q_,     2 * Q_);
    rescore_gemm<false, true ><<<dim3(1024), blk, 0, stream>>>(H1F, W2, H2F, FLAGS, CNT, 2 * Q_, Q_);
    rescore_gemm<false, false><<<dim3(1024), blk, 0, stream>>>(H2F, W3, SCF, FLAGS, CNT, Q_,     Q_);
    rescore_argmax<<<dim3(64), blk, 0, stream>>>(SCF, FLAGS, CNT, KV);
    // stable top-k mask on x (bf16 {0,1})
    topk_mask<<<dim3(B_), dim3(512), 0, stream>>>(x, KV, MASKB);
    // out = mask @ Wc^T (plain bf16 MFMA)
    gemm3p<1, false, false, false><<<dim3(E_ / 128, B_ / 128), blk, 0, stream>>>(
        MASKB, nullptr, Wc, out, nullptr, B_, E_, Q_);
}

// Round 4
// 2154.772 us; speedup vs baseline: 3.4218x; 1.2606x over previous
//
#include <hip/hip_runtime.h>
#include <stdint.h>

#define B_  32768
#define Q_  1024
#define E_  1024
#define CAPF 16384   // max flagged rows the rescore scratch layout supports

typedef __attribute__((ext_vector_type(8))) short bf16x8;
typedef __attribute__((ext_vector_type(8))) unsigned short u16x8;
typedef __attribute__((ext_vector_type(4))) float f32x4;

__device__ __forceinline__ f32x4 MFMA16(bf16x8 a, bf16x8 b, f32x4 c) {
    return __builtin_amdgcn_mfma_f32_16x16x32_bf16(a, b, c, 0, 0, 0);
}

__device__ __forceinline__ unsigned short f2bf(float v) {   // RNE fp32->bf16
    unsigned u = __float_as_uint(v);
    u += 0x7FFFu + ((u >> 16) & 1u);
    return (unsigned short)(u >> 16);
}
__device__ __forceinline__ float bf2f(unsigned short b) {
    return __uint_as_float(((unsigned)b) << 16);
}

// 16B-chunk index inside a 128x32-bf16 LDS tile, XOR-swizzled so the MFMA
// fragment read (16 lanes = 16 consecutive rows, same koff) spreads banks.
__device__ __forceinline__ int chunk_of(int row, int koff) {
    return row * 4 + (koff ^ (row & 3));
}

template<int NPASS>
__device__ __forceinline__ void split_store(unsigned short* S0, unsigned short* S1,
                                            int rowX, int koffX, float4 a, float4 b) {
    int ch = chunk_of(rowX, koffX);
    float f[8] = {a.x, a.y, a.z, a.w, b.x, b.y, b.z, b.w};
    bf16x8 lo, hi;
#pragma unroll
    for (int j = 0; j < 8; ++j) {
        unsigned short c0 = f2bf(f[j]);
        lo[j] = (short)c0;
        hi[j] = (short)f2bf(f[j] - bf2f(c0));   // exact residual (Sterbenz)
    }
    *(bf16x8*)&S0[ch * 8] = lo;
    if constexpr (NPASS == 3) *(bf16x8*)&S1[ch * 8] = hi;
}

// C[M,N] = act(A @ W^T) via split-bf16 MFMA.
//   NPASS=3: acc = A0B0 + A0B1 + A1B0 (fp32-grade);  NPASS=1: plain bf16.
template<int NPASS, bool AF32, bool RELU, bool EMITP>
__global__ __launch_bounds__(256, 2)
void gemm3p(const void* __restrict__ Ap0, const void* __restrict__ Ap1,
            const float* __restrict__ Wf,
            void* __restrict__ Cp0, void* __restrict__ Cp1,
            int M, int N, int K) {
    __shared__ __align__(16) unsigned short A0s[128 * 32];
    __shared__ __align__(16) unsigned short B0s[128 * 32];
    __shared__ __align__(16) unsigned short A1s[(NPASS == 3) ? 128 * 32 : 8];
    __shared__ __align__(16) unsigned short B1s[(NPASS == 3) ? 128 * 32 : 8];

    const int t = threadIdx.x;
    const int wave = t >> 6, lane = t & 63;
    const int lanelo = lane & 15, kq = lane >> 4;
    const int wm = wave >> 1, wn = wave & 1;
    const int m0 = blockIdx.y * 128, n0 = blockIdx.x * 128;
    const int brow = t >> 1, bhalf = t & 1;

    f32x4 acc[4][4];
#pragma unroll
    for (int i = 0; i < 4; ++i)
#pragma unroll
        for (int j = 0; j < 4; ++j) acc[i][j] = (f32x4){0.f, 0.f, 0.f, 0.f};

    for (int kt = 0; kt < K; kt += 32) {
        __syncthreads();
        const float* wp = Wf + (size_t)(n0 + brow) * K + kt + bhalf * 16;
        float4 v0 = *(const float4*)(wp + 0);
        float4 v1 = *(const float4*)(wp + 4);
        float4 v2 = *(const float4*)(wp + 8);
        float4 v3 = *(const float4*)(wp + 12);
        if constexpr (AF32) {
            const float* ap = (const float*)Ap0 + (size_t)(m0 + brow) * K + kt + bhalf * 16;
            float4 u0 = *(const float4*)(ap + 0);
            float4 u1 = *(const float4*)(ap + 4);
            float4 u2 = *(const float4*)(ap + 8);
            float4 u3 = *(const float4*)(ap + 12);
            split_store<NPASS>(A0s, A1s, brow, bhalf * 2 + 0, u0, u1);
            split_store<NPASS>(A0s, A1s, brow, bhalf * 2 + 1, u2, u3);
        } else {
#pragma unroll
            for (int g = 0; g < 2; ++g) {
                int c = (g * 4 + wave) * 64 + lane;
                int row = c >> 2;
                int koff = (c & 3) ^ (row & 3);
                const unsigned short* s0 =
                    (const unsigned short*)Ap0 + (size_t)(m0 + row) * K + kt + koff * 8;
                __builtin_amdgcn_global_load_lds(
                    (const __attribute__((address_space(1))) void*)s0,
                    (__attribute__((address_space(3))) void*)&A0s[(size_t)(g * 4 + wave) * 64 * 8],
                    16, 0, 0);
                if constexpr (NPASS == 3) {
                    const unsigned short* s1 =
                        (const unsigned short*)Ap1 + (size_t)(m0 + row) * K + kt + koff * 8;
                    __builtin_amdgcn_global_load_lds(
                        (const __attribute__((address_space(1))) void*)s1,
                        (__attribute__((address_space(3))) void*)&A1s[(size_t)(g * 4 + wave) * 64 * 8],
                        16, 0, 0);
                }
            }
        }
        split_store<NPASS>(B0s, B1s, brow, bhalf * 2 + 0, v0, v1);
        split_store<NPASS>(B0s, B1s, brow, bhalf * 2 + 1, v2, v3);
        __syncthreads();

        bf16x8 a0[4], a1[4];
#pragma unroll
        for (int mf = 0; mf < 4; ++mf) {
            int ar = wm * 64 + mf * 16 + lanelo;
            int ac = chunk_of(ar, kq);
            a0[mf] = *(const bf16x8*)&A0s[ac * 8];
            if constexpr (NPASS == 3) a1[mf] = *(const bf16x8*)&A1s[ac * 8];
        }
#pragma unroll
        for (int nf = 0; nf < 4; ++nf) {
            int br = wn * 64 + nf * 16 + lanelo;
            int bc = chunk_of(br, kq);
            bf16x8 vb0 = *(const bf16x8*)&B0s[bc * 8];
#pragma unroll
            for (int mf = 0; mf < 4; ++mf) acc[mf][nf] = MFMA16(a0[mf], vb0, acc[mf][nf]);
            if constexpr (NPASS == 3) {
                bf16x8 vb1 = *(const bf16x8*)&B1s[bc * 8];
#pragma unroll
                for (int mf = 0; mf < 4; ++mf) acc[mf][nf] = MFMA16(a0[mf], vb1, acc[mf][nf]);
#pragma unroll
                for (int mf = 0; mf < 4; ++mf) acc[mf][nf] = MFMA16(a1[mf], vb0, acc[mf][nf]);
            }
        }
    }

    // C/D layout: col=lane&15, row=(lane>>4)*4+reg (m89/m91)
#pragma unroll
    for (int mf = 0; mf < 4; ++mf)
#pragma unroll
        for (int nf = 0; nf < 4; ++nf)
#pragma unroll
            for (int r = 0; r < 4; ++r) {
                int row = m0 + wm * 64 + mf * 16 + kq * 4 + r;
                int col = n0 + wn * 64 + nf * 16 + lanelo;
                float v = acc[mf][nf][r];
                if constexpr (RELU) v = fmaxf(v, 0.f);
                if constexpr (EMITP) {
                    unsigned short c0 = f2bf(v);
                    ((unsigned short*)Cp0)[(size_t)row * N + col] = c0;
                    ((unsigned short*)Cp1)[(size_t)row * N + col] = f2bf(v - bf2f(c0));
                } else {
                    ((float*)Cp0)[(size_t)row * N + col] = v;
                }
            }
}

// k[row] = argmax+1 (first occurrence); flag rows whose top-2 gap < theta
__global__ __launch_bounds__(256)
void row_argmax_flag(const float* __restrict__ S, int* __restrict__ KV,
                     int* __restrict__ flags, int* __restrict__ cnt) {
    int row = blockIdx.x * 4 + (threadIdx.x >> 6);
    int lane = threadIdx.x & 63;
    const float* s = S + (size_t)row * Q_;
    float b1 = -3.4e38f, b2 = -3.4e38f; int i1 = 0;
    for (int j = lane; j < Q_; j += 64) {
        float v = s[j];
        if (v > b1) { b2 = b1; b1 = v; i1 = j; }
        else if (v > b2) b2 = v;
    }
#pragma unroll
    for (int m = 1; m < 64; m <<= 1) {
        float o1 = __shfl_xor(b1, m);
        int   oi = __shfl_xor(i1, m);
        float o2 = __shfl_xor(b2, m);
        if (o1 > b1 || (o1 == b1 && oi < i1)) {
            b2 = fmaxf(b1, o2);
            b1 = o1; i1 = oi;
        } else {
            b2 = fmaxf(b2, o1);
        }
    }
    if (lane == 0) {
        KV[row] = i1 + 1;
        if (b1 - b2 < 1e-3f) { int p = atomicAdd(cnt, 1); flags[p] = row; }
    }
}

// ---- parallel coalesced rescore: one wave per output column, fp64 accum ----
template<bool IN_BY_FLAG, bool RELU>
__global__ __launch_bounds__(256)
void rescore_gemm(const float* __restrict__ IN, const float* __restrict__ W,
                  float* __restrict__ OUT, const int* __restrict__ flags,
                  const int* __restrict__ cnt, int K, int N) {
    __shared__ float xr[2 * Q_];
    const int t = threadIdx.x, lane = t & 63, wv = t >> 6;
    const int n = min(*cnt, CAPF);
    const int chunks = N >> 4;
    for (int w = blockIdx.x; w < n * chunks; w += gridDim.x) {
        const int it = w / chunks, ch = w - it * chunks;
        const float* rp = IN_BY_FLAG ? IN + (size_t)flags[it] * K
                                     : IN + (size_t)it * K;
        __syncthreads();
        for (int p = t; p < K; p += 256) xr[p] = rp[p];
        __syncthreads();
#pragma unroll
        for (int jj = 0; jj < 4; ++jj) {
            const int col = ch * 16 + wv * 4 + jj;
            const float* wr = W + (size_t)col * K;
            double a = 0.0;
            for (int k = lane; k < K; k += 64)
                a += (double)xr[k] * (double)wr[k];
#pragma unroll
            for (int m = 1; m < 64; m <<= 1) a += __shfl_xor(a, m);
            if (lane == 0) {
                float v = (float)a;
                if (RELU) v = fmaxf(v, 0.f);
                OUT[(size_t)it * N + col] = v;
            }
        }
    }
}

// final exact argmax over rescored score rows, first-occurrence tie-break
__global__ __launch_bounds__(256)
void rescore_argmax(const float* __restrict__ SCF, const int* __restrict__ flags,
                    const int* __restrict__ cnt, int* __restrict__ KV) {
    const int lane = threadIdx.x & 63, wv = threadIdx.x >> 6;
    const int n = min(*cnt, CAPF);
    for (int it = blockIdx.x * 4 + wv; it < n; it += gridDim.x * 4) {
        const float* s = SCF + (size_t)it * Q_;
        float best = -3.4e38f; int bi = 0;
        for (int j = lane; j < Q_; j += 64) {
            float v = s[j];
            if (v > best) { best = v; bi = j; }
        }
#pragma unroll
        for (int m = 1; m < 64; m <<= 1) {
            float ov = __shfl_xor(best, m); int oi = __shfl_xor(bi, m);
            if (ov > best || (ov == best && oi < bi)) { best = ov; bi = oi; }
        }
        if (lane == 0) KV[flags[it]] = bi + 1;
    }
}

// ---- stable top-k mask via in-register bit-descent radix select ----
// One wave per row; lane l owns contiguous elements [16l, 16l+16).
// T = k-th largest orderable key (exact); mask = (u>T) plus the first
// (k - count(u>T)) elements equal to T in ascending index order — exactly
// the reference's stable argsort(argsort(-x)) < k semantics.
__global__ __launch_bounds__(256)
void topk_mask_radix(const float* __restrict__ X, const int* __restrict__ KV,
                     unsigned short* __restrict__ Mout) {
    const int row  = blockIdx.x * 4 + (threadIdx.x >> 6);
    const int lane = threadIdx.x & 63;
    const float* x = X + (size_t)row * Q_;

    unsigned u[16];
#pragma unroll
    for (int j4 = 0; j4 < 4; ++j4) {
        float4 v = *(const float4*)(x + lane * 16 + j4 * 4);
        float f[4] = {v.x, v.y, v.z, v.w};
#pragma unroll
        for (int e = 0; e < 4; ++e) {
            unsigned fb = __float_as_uint(f[e]);
            u[j4 * 4 + e] = (fb & 0x80000000u) ? ~fb : (fb | 0x80000000u);
        }
    }
    const int k = KV[row];

    // bit-descent: largest T with count(u >= T) >= k  (== k-th largest key)
    unsigned p = 0;
#pragma unroll
    for (int b = 31; b >= 0; --b) {
        unsigned q = p | (1u << b);
        int c = 0;
#pragma unroll
        for (int j = 0; j < 16; ++j) c += (u[j] >= q);
#pragma unroll
        for (int m = 1; m < 64; m <<= 1) c += __shfl_xor(c, m);
        if (c >= k) p = q;
    }

    // strict-greater count and per-lane equal count
    int gt = 0, eqloc = 0;
#pragma unroll
    for (int j = 0; j < 16; ++j) { gt += (u[j] > p); eqloc += (u[j] == p); }
    int gtot = gt;
#pragma unroll
    for (int m = 1; m < 64; m <<= 1) gtot += __shfl_xor(gtot, m);
    // exclusive scan of equal counts across lanes (= ascending index order)
    int scan = eqloc;
#pragma unroll
    for (int d = 1; d < 64; d <<= 1) {
        int o = __shfl_up(scan, d);
        if (lane >= d) scan += o;
    }
    int run = scan - eqloc;          // equals in lower indices
    const int quota = k - gtot;      // how many equal-to-T elements get a 1

    unsigned short m16[16];
#pragma unroll
    for (int j = 0; j < 16; ++j) {
        bool one;
        if (u[j] > p) one = true;
        else if (u[j] == p) { one = (run < quota); ++run; }
        else one = false;
        m16[j] = one ? (unsigned short)0x3F80 : (unsigned short)0;
    }
    u16x8* dst = (u16x8*)(Mout + (size_t)row * Q_ + lane * 16);
    dst[0] = *(u16x8*)&m16[0];
    dst[1] = *(u16x8*)&m16[8];
}

extern "C" void kernel_launch(void* const* d_in, const int* in_sizes, int n_in,
                              void* d_out, int out_size, void* d_ws, size_t ws_size,
                              hipStream_t stream) {
    const float* x  = (const float*)d_in[0];
    const float* W1 = (const float*)d_in[1];   // [2Q, Q]
    const float* W2 = (const float*)d_in[2];   // [Q, 2Q]
    const float* W3 = (const float*)d_in[3];   // [Q, Q]
    const float* Wc = (const float*)d_in[4];   // [E, Q]
    float* out = (float*)d_out;

    char* ws = (char*)d_ws;
    unsigned short* H1_0 = (unsigned short*)ws;                         // [B,2Q] bf16 hi
    unsigned short* H1_1 = (unsigned short*)(ws + ((size_t)128 << 20)); // [B,2Q] bf16 lo
    float*          SC   = (float*)ws;                                  // scores (aliases H1_0, dead)
    unsigned short* MASKB= (unsigned short*)(ws + ((size_t)128 << 20)); // mask bf16 (aliases H1_1)
    int* KV    = (int*)(ws + ((size_t)256 << 20));
    int* FLAGS = KV + B_;
    int* CNT   = FLAGS + B_;
    unsigned short* H2_0 = (unsigned short*)d_out;                      // [B,Q] bf16 hi
    unsigned short* H2_1 = (unsigned short*)d_out + (size_t)B_ * Q_;    // [B,Q] bf16 lo
    float* H1F = (float*)ws;                                            // [n,2Q] fp32
    float* H2F = (float*)(ws + ((size_t)128 << 20));                    // [n,Q]
    float* SCF = (float*)(ws + ((size_t)192 << 20));                    // [n,Q]

    hipMemsetAsync(CNT, 0, sizeof(int), stream);
    dim3 blk(256);
    gemm3p<3, true,  true,  true ><<<dim3(2 * Q_ / 128, B_ / 128), blk, 0, stream>>>(
        x, nullptr, W1, H1_0, H1_1, B_, 2 * Q_, Q_);
    gemm3p<3, false, true,  true ><<<dim3(Q_ / 128, B_ / 128), blk, 0, stream>>>(
        H1_0, H1_1, W2, H2_0, H2_1, B_, Q_, 2 * Q_);
    gemm3p<3, false, false, false><<<dim3(Q_ / 128, B_ / 128), blk, 0, stream>>>(
        H2_0, H2_1, W3, SC, nullptr, B_, Q_, Q_);
    row_argmax_flag<<<dim3(B_ / 4), blk, 0, stream>>>(SC, KV, FLAGS, CNT);
    rescore_gemm<true,  true ><<<dim3(2048), blk, 0, stream>>>(x,   W1, H1F, FLAGS, CNT, Q_,     2 * Q_);
    rescore_gemm<false, true ><<<dim3(1024), blk, 0, stream>>>(H1F, W2, H2F, FLAGS, CNT, 2 * Q_, Q_);
    rescore_gemm<false, false><<<dim3(1024), blk, 0, stream>>>(H2F, W3, SCF, FLAGS, CNT, Q_,     Q_);
    rescore_argmax<<<dim3(64), blk, 0, stream>>>(SCF, FLAGS, CNT, KV);
    topk_mask_radix<<<dim3(B_ / 4), blk, 0, stream>>>(x, KV, MASKB);
    gemm3p<1, false, false, false><<<dim3(E_ / 128, B_ / 128), blk, 0, stream>>>(
        MASKB, nullptr, Wc, out, nullptr, B_, E_, Q_);
}

// Round 5
// 1999.289 us; speedup vs baseline: 3.6879x; 1.0778x over previous
//
#include <hip/hip_runtime.h>
#include <stdint.h>

#define B_  32768
#define Q_  1024
#define E_  1024
#define CAPF 16384   // max flagged rows the rescore scratch layout supports

typedef __attribute__((ext_vector_type(8))) short bf16x8;
typedef __attribute__((ext_vector_type(8))) unsigned short u16x8;
typedef __attribute__((ext_vector_type(4))) float f32x4;

__device__ __forceinline__ f32x4 MFMA16(bf16x8 a, bf16x8 b, f32x4 c) {
    return __builtin_amdgcn_mfma_f32_16x16x32_bf16(a, b, c, 0, 0, 0);
}

__device__ __forceinline__ unsigned short f2bf(float v) {   // RNE fp32->bf16
    unsigned u = __float_as_uint(v);
    u += 0x7FFFu + ((u >> 16) & 1u);
    return (unsigned short)(u >> 16);
}
__device__ __forceinline__ float bf2f(unsigned short b) {
    return __uint_as_float(((unsigned)b) << 16);
}

// 16B-chunk index inside a 128x32-bf16 LDS tile, XOR-swizzled so the MFMA
// fragment read (16 lanes = 16 consecutive rows, same koff) spreads banks.
__device__ __forceinline__ int chunk_of(int row, int koff) {
    return row * 4 + (koff ^ (row & 3));
}

// ---------------- plane prep (hoisted split: runs ONCE, memory-bound) -------
__global__ __launch_bounds__(256)
void split_planes_k(const float* __restrict__ in, unsigned short* __restrict__ hi,
                    unsigned short* __restrict__ lo, int n8) {
    int i = blockIdx.x * 256 + threadIdx.x;
    const int stride = gridDim.x * 256;
    for (; i < n8; i += stride) {
        float4 a = ((const float4*)in)[i * 2];
        float4 b = ((const float4*)in)[i * 2 + 1];
        float f[8] = {a.x, a.y, a.z, a.w, b.x, b.y, b.z, b.w};
        u16x8 h, l;
#pragma unroll
        for (int j = 0; j < 8; ++j) {
            unsigned short c0 = f2bf(f[j]);
            h[j] = c0;
            l[j] = f2bf(f[j] - bf2f(c0));   // exact residual (Sterbenz)
        }
        ((u16x8*)hi)[i] = h;
        ((u16x8*)lo)[i] = l;
    }
}

__global__ __launch_bounds__(256)
void cvt_plane_k(const float* __restrict__ in, unsigned short* __restrict__ hi, int n8) {
    int i = blockIdx.x * 256 + threadIdx.x;
    const int stride = gridDim.x * 256;
    for (; i < n8; i += stride) {
        float4 a = ((const float4*)in)[i * 2];
        float4 b = ((const float4*)in)[i * 2 + 1];
        float f[8] = {a.x, a.y, a.z, a.w, b.x, b.y, b.z, b.w};
        u16x8 h;
#pragma unroll
        for (int j = 0; j < 8; ++j) h[j] = f2bf(f[j]);
        ((u16x8*)hi)[i] = h;
    }
}

// ---------------- all-plane GEMM: A,B both bf16 planes via global_load_lds --
//   NPASS=3: acc = A0B0 + A0B1 + A1B0 (fp32-grade);  NPASS=1: plain bf16.
// 1-D grid with bijective XCD swizzle (m204): 8 consecutive logical blocks
// (same m-panel, all n) land on one XCD -> A panel L2 reuse.
template<int NPASS, bool RELU, bool EMITP>
__global__ __launch_bounds__(256, 4)
void gemm_pp(const unsigned short* __restrict__ A0, const unsigned short* __restrict__ A1,
             const unsigned short* __restrict__ B0, const unsigned short* __restrict__ B1,
             void* __restrict__ Cp0, void* __restrict__ Cp1,
             int M, int N, int K) {
    __shared__ __align__(16) unsigned short A0s[128 * 32];
    __shared__ __align__(16) unsigned short B0s[128 * 32];
    __shared__ __align__(16) unsigned short A1s[(NPASS == 3) ? 128 * 32 : 8];
    __shared__ __align__(16) unsigned short B1s[(NPASS == 3) ? 128 * 32 : 8];

    const int t = threadIdx.x;
    const int wave = t >> 6, lane = t & 63;
    const int lanelo = lane & 15, kq = lane >> 4;
    const int wm = wave >> 1, wn = wave & 1;
    const int q8 = gridDim.x >> 3;                 // grid divisible by 8
    const int logical = (blockIdx.x & 7) * q8 + (blockIdx.x >> 3);
    const int gx = N >> 7;
    const int m0 = (logical / gx) * 128, n0 = (logical % gx) * 128;

    f32x4 acc[4][4];
#pragma unroll
    for (int i = 0; i < 4; ++i)
#pragma unroll
        for (int j = 0; j < 4; ++j) acc[i][j] = (f32x4){0.f, 0.f, 0.f, 0.f};

    for (int kt = 0; kt < K; kt += 32) {
        __syncthreads();   // prior compute done before LDS overwrite
#pragma unroll
        for (int g = 0; g < 2; ++g) {
            int c = (g * 4 + wave) * 64 + lane;
            int row = c >> 2;
            int koff = (c & 3) ^ (row & 3);        // pre-swizzled source (rule #21)
            size_t offa = (size_t)(m0 + row) * K + kt + koff * 8;
            size_t offb = (size_t)(n0 + row) * K + kt + koff * 8;
            int dst = (g * 4 + wave) * 512;
            __builtin_amdgcn_global_load_lds(
                (const __attribute__((address_space(1))) void*)(A0 + offa),
                (__attribute__((address_space(3))) void*)&A0s[dst], 16, 0, 0);
            __builtin_amdgcn_global_load_lds(
                (const __attribute__((address_space(1))) void*)(B0 + offb),
                (__attribute__((address_space(3))) void*)&B0s[dst], 16, 0, 0);
            if constexpr (NPASS == 3) {
                __builtin_amdgcn_global_load_lds(
                    (const __attribute__((address_space(1))) void*)(A1 + offa),
                    (__attribute__((address_space(3))) void*)&A1s[dst], 16, 0, 0);
                __builtin_amdgcn_global_load_lds(
                    (const __attribute__((address_space(1))) void*)(B1 + offb),
                    (__attribute__((address_space(3))) void*)&B1s[dst], 16, 0, 0);
            }
        }
        __syncthreads();   // drains vmcnt before fragment reads

        bf16x8 a0[4], a1[4];
#pragma unroll
        for (int mf = 0; mf < 4; ++mf) {
            int ar = wm * 64 + mf * 16 + lanelo;
            int ac = chunk_of(ar, kq);
            a0[mf] = *(const bf16x8*)&A0s[ac * 8];
            if constexpr (NPASS == 3) a1[mf] = *(const bf16x8*)&A1s[ac * 8];
        }
#pragma unroll
        for (int nf = 0; nf < 4; ++nf) {
            int br = wn * 64 + nf * 16 + lanelo;
            int bc = chunk_of(br, kq);
            bf16x8 vb0 = *(const bf16x8*)&B0s[bc * 8];
#pragma unroll
            for (int mf = 0; mf < 4; ++mf) acc[mf][nf] = MFMA16(a0[mf], vb0, acc[mf][nf]);
            if constexpr (NPASS == 3) {
                bf16x8 vb1 = *(const bf16x8*)&B1s[bc * 8];
#pragma unroll
                for (int mf = 0; mf < 4; ++mf) acc[mf][nf] = MFMA16(a0[mf], vb1, acc[mf][nf]);
#pragma unroll
                for (int mf = 0; mf < 4; ++mf) acc[mf][nf] = MFMA16(a1[mf], vb0, acc[mf][nf]);
            }
        }
    }

    // C/D layout: col=lane&15, row=(lane>>4)*4+reg (m89/m91)
#pragma unroll
    for (int mf = 0; mf < 4; ++mf)
#pragma unroll
        for (int nf = 0; nf < 4; ++nf)
#pragma unroll
            for (int r = 0; r < 4; ++r) {
                int row = m0 + wm * 64 + mf * 16 + kq * 4 + r;
                int col = n0 + wn * 64 + nf * 16 + lanelo;
                float v = acc[mf][nf][r];
                if constexpr (RELU) v = fmaxf(v, 0.f);
                if constexpr (EMITP) {
                    unsigned short c0 = f2bf(v);
                    ((unsigned short*)Cp0)[(size_t)row * N + col] = c0;
                    ((unsigned short*)Cp1)[(size_t)row * N + col] = f2bf(v - bf2f(c0));
                } else {
                    ((float*)Cp0)[(size_t)row * N + col] = v;
                }
            }
}

// ---------------- fallback GEMM (round-4, in-kernel split) ------------------
template<int NPASS>
__device__ __forceinline__ void split_store(unsigned short* S0, unsigned short* S1,
                                            int rowX, int koffX, float4 a, float4 b) {
    int ch = chunk_of(rowX, koffX);
    float f[8] = {a.x, a.y, a.z, a.w, b.x, b.y, b.z, b.w};
    bf16x8 lo, hi;
#pragma unroll
    for (int j = 0; j < 8; ++j) {
        unsigned short c0 = f2bf(f[j]);
        lo[j] = (short)c0;
        hi[j] = (short)f2bf(f[j] - bf2f(c0));
    }
    *(bf16x8*)&S0[ch * 8] = lo;
    if constexpr (NPASS == 3) *(bf16x8*)&S1[ch * 8] = hi;
}

template<int NPASS, bool AF32, bool RELU, bool EMITP>
__global__ __launch_bounds__(256, 2)
void gemm3p(const void* __restrict__ Ap0, const void* __restrict__ Ap1,
            const float* __restrict__ Wf,
            void* __restrict__ Cp0, void* __restrict__ Cp1,
            int M, int N, int K) {
    __shared__ __align__(16) unsigned short A0s[128 * 32];
    __shared__ __align__(16) unsigned short B0s[128 * 32];
    __shared__ __align__(16) unsigned short A1s[(NPASS == 3) ? 128 * 32 : 8];
    __shared__ __align__(16) unsigned short B1s[(NPASS == 3) ? 128 * 32 : 8];

    const int t = threadIdx.x;
    const int wave = t >> 6, lane = t & 63;
    const int lanelo = lane & 15, kq = lane >> 4;
    const int wm = wave >> 1, wn = wave & 1;
    const int m0 = blockIdx.y * 128, n0 = blockIdx.x * 128;
    const int brow = t >> 1, bhalf = t & 1;

    f32x4 acc[4][4];
#pragma unroll
    for (int i = 0; i < 4; ++i)
#pragma unroll
        for (int j = 0; j < 4; ++j) acc[i][j] = (f32x4){0.f, 0.f, 0.f, 0.f};

    for (int kt = 0; kt < K; kt += 32) {
        __syncthreads();
        const float* wp = Wf + (size_t)(n0 + brow) * K + kt + bhalf * 16;
        float4 v0 = *(const float4*)(wp + 0);
        float4 v1 = *(const float4*)(wp + 4);
        float4 v2 = *(const float4*)(wp + 8);
        float4 v3 = *(const float4*)(wp + 12);
        if constexpr (AF32) {
            const float* ap = (const float*)Ap0 + (size_t)(m0 + brow) * K + kt + bhalf * 16;
            float4 u0 = *(const float4*)(ap + 0);
            float4 u1 = *(const float4*)(ap + 4);
            float4 u2 = *(const float4*)(ap + 8);
            float4 u3 = *(const float4*)(ap + 12);
            split_store<NPASS>(A0s, A1s, brow, bhalf * 2 + 0, u0, u1);
            split_store<NPASS>(A0s, A1s, brow, bhalf * 2 + 1, u2, u3);
        } else {
#pragma unroll
            for (int g = 0; g < 2; ++g) {
                int c = (g * 4 + wave) * 64 + lane;
                int row = c >> 2;
                int koff = (c & 3) ^ (row & 3);
                const unsigned short* s0 =
                    (const unsigned short*)Ap0 + (size_t)(m0 + row) * K + kt + koff * 8;
                __builtin_amdgcn_global_load_lds(
                    (const __attribute__((address_space(1))) void*)s0,
                    (__attribute__((address_space(3))) void*)&A0s[(size_t)(g * 4 + wave) * 64 * 8],
                    16, 0, 0);
                if constexpr (NPASS == 3) {
                    const unsigned short* s1 =
                        (const unsigned short*)Ap1 + (size_t)(m0 + row) * K + kt + koff * 8;
                    __builtin_amdgcn_global_load_lds(
                        (const __attribute__((address_space(1))) void*)s1,
                        (__attribute__((address_space(3))) void*)&A1s[(size_t)(g * 4 + wave) * 64 * 8],
                        16, 0, 0);
                }
            }
        }
        split_store<NPASS>(B0s, B1s, brow, bhalf * 2 + 0, v0, v1);
        split_store<NPASS>(B0s, B1s, brow, bhalf * 2 + 1, v2, v3);
        __syncthreads();

        bf16x8 a0[4], a1[4];
#pragma unroll
        for (int mf = 0; mf < 4; ++mf) {
            int ar = wm * 64 + mf * 16 + lanelo;
            int ac = chunk_of(ar, kq);
            a0[mf] = *(const bf16x8*)&A0s[ac * 8];
            if constexpr (NPASS == 3) a1[mf] = *(const bf16x8*)&A1s[ac * 8];
        }
#pragma unroll
        for (int nf = 0; nf < 4; ++nf) {
            int br = wn * 64 + nf * 16 + lanelo;
            int bc = chunk_of(br, kq);
            bf16x8 vb0 = *(const bf16x8*)&B0s[bc * 8];
#pragma unroll
            for (int mf = 0; mf < 4; ++mf) acc[mf][nf] = MFMA16(a0[mf], vb0, acc[mf][nf]);
            if constexpr (NPASS == 3) {
                bf16x8 vb1 = *(const bf16x8*)&B1s[bc * 8];
#pragma unroll
                for (int mf = 0; mf < 4; ++mf) acc[mf][nf] = MFMA16(a0[mf], vb1, acc[mf][nf]);
#pragma unroll
                for (int mf = 0; mf < 4; ++mf) acc[mf][nf] = MFMA16(a1[mf], vb0, acc[mf][nf]);
            }
        }
    }

#pragma unroll
    for (int mf = 0; mf < 4; ++mf)
#pragma unroll
        for (int nf = 0; nf < 4; ++nf)
#pragma unroll
            for (int r = 0; r < 4; ++r) {
                int row = m0 + wm * 64 + mf * 16 + kq * 4 + r;
                int col = n0 + wn * 64 + nf * 16 + lanelo;
                float v = acc[mf][nf][r];
                if constexpr (RELU) v = fmaxf(v, 0.f);
                if constexpr (EMITP) {
                    unsigned short c0 = f2bf(v);
                    ((unsigned short*)Cp0)[(size_t)row * N + col] = c0;
                    ((unsigned short*)Cp1)[(size_t)row * N + col] = f2bf(v - bf2f(c0));
                } else {
                    ((float*)Cp0)[(size_t)row * N + col] = v;
                }
            }
}

// k[row] = argmax+1 (first occurrence); flag rows whose top-2 gap < theta
__global__ __launch_bounds__(256)
void row_argmax_flag(const float* __restrict__ S, int* __restrict__ KV,
                     int* __restrict__ flags, int* __restrict__ cnt) {
    int row = blockIdx.x * 4 + (threadIdx.x >> 6);
    int lane = threadIdx.x & 63;
    const float* s = S + (size_t)row * Q_;
    float b1 = -3.4e38f, b2 = -3.4e38f; int i1 = 0;
    for (int j = lane; j < Q_; j += 64) {
        float v = s[j];
        if (v > b1) { b2 = b1; b1 = v; i1 = j; }
        else if (v > b2) b2 = v;
    }
#pragma unroll
    for (int m = 1; m < 64; m <<= 1) {
        float o1 = __shfl_xor(b1, m);
        int   oi = __shfl_xor(i1, m);
        float o2 = __shfl_xor(b2, m);
        if (o1 > b1 || (o1 == b1 && oi < i1)) {
            b2 = fmaxf(b1, o2);
            b1 = o1; i1 = oi;
        } else {
            b2 = fmaxf(b2, o1);
        }
    }
    if (lane == 0) {
        KV[row] = i1 + 1;
        if (b1 - b2 < 1e-3f) { int p = atomicAdd(cnt, 1); flags[p] = row; }
    }
}

// ---- parallel coalesced rescore: one wave per output column, fp64 accum ----
template<bool IN_BY_FLAG, bool RELU>
__global__ __launch_bounds__(256)
void rescore_gemm(const float* __restrict__ IN, const float* __restrict__ W,
                  float* __restrict__ OUT, const int* __restrict__ flags,
                  const int* __restrict__ cnt, int K, int N) {
    __shared__ float xr[2 * Q_];
    const int t = threadIdx.x, lane = t & 63, wv = t >> 6;
    const int n = min(*cnt, CAPF);
    const int chunks = N >> 4;
    for (int w = blockIdx.x; w < n * chunks; w += gridDim.x) {
        const int it = w / chunks, ch = w - it * chunks;
        const float* rp = IN_BY_FLAG ? IN + (size_t)flags[it] * K
                                     : IN + (size_t)it * K;
        __syncthreads();
        for (int p = t; p < K; p += 256) xr[p] = rp[p];
        __syncthreads();
#pragma unroll
        for (int jj = 0; jj < 4; ++jj) {
            const int col = ch * 16 + wv * 4 + jj;
            const float* wr = W + (size_t)col * K;
            double a = 0.0;
            for (int k = lane; k < K; k += 64)
                a += (double)xr[k] * (double)wr[k];
#pragma unroll
            for (int m = 1; m < 64; m <<= 1) a += __shfl_xor(a, m);
            if (lane == 0) {
                float v = (float)a;
                if (RELU) v = fmaxf(v, 0.f);
                OUT[(size_t)it * N + col] = v;
            }
        }
    }
}

// final exact argmax over rescored score rows, first-occurrence tie-break
__global__ __launch_bounds__(256)
void rescore_argmax(const float* __restrict__ SCF, const int* __restrict__ flags,
                    const int* __restrict__ cnt, int* __restrict__ KV) {
    const int lane = threadIdx.x & 63, wv = threadIdx.x >> 6;
    const int n = min(*cnt, CAPF);
    for (int it = blockIdx.x * 4 + wv; it < n; it += gridDim.x * 4) {
        const float* s = SCF + (size_t)it * Q_;
        float best = -3.4e38f; int bi = 0;
        for (int j = lane; j < Q_; j += 64) {
            float v = s[j];
            if (v > best) { best = v; bi = j; }
        }
#pragma unroll
        for (int m = 1; m < 64; m <<= 1) {
            float ov = __shfl_xor(best, m); int oi = __shfl_xor(bi, m);
            if (ov > best || (ov == best && oi < bi)) { best = ov; bi = oi; }
        }
        if (lane == 0) KV[flags[it]] = bi + 1;
    }
}

// ---- stable top-k mask via in-register bit-descent radix select ----
__global__ __launch_bounds__(256)
void topk_mask_radix(const float* __restrict__ X, const int* __restrict__ KV,
                     unsigned short* __restrict__ Mout) {
    const int row  = blockIdx.x * 4 + (threadIdx.x >> 6);
    const int lane = threadIdx.x & 63;
    const float* x = X + (size_t)row * Q_;

    unsigned u[16];
#pragma unroll
    for (int j4 = 0; j4 < 4; ++j4) {
        float4 v = *(const float4*)(x + lane * 16 + j4 * 4);
        float f[4] = {v.x, v.y, v.z, v.w};
#pragma unroll
        for (int e = 0; e < 4; ++e) {
            unsigned fb = __float_as_uint(f[e]);
            u[j4 * 4 + e] = (fb & 0x80000000u) ? ~fb : (fb | 0x80000000u);
        }
    }
    const int k = KV[row];

    unsigned p = 0;
#pragma unroll
    for (int b = 31; b >= 0; --b) {
        unsigned q = p | (1u << b);
        int c = 0;
#pragma unroll
        for (int j = 0; j < 16; ++j) c += (u[j] >= q);
#pragma unroll
        for (int m = 1; m < 64; m <<= 1) c += __shfl_xor(c, m);
        if (c >= k) p = q;
    }

    int gt = 0, eqloc = 0;
#pragma unroll
    for (int j = 0; j < 16; ++j) { gt += (u[j] > p); eqloc += (u[j] == p); }
    int gtot = gt;
#pragma unroll
    for (int m = 1; m < 64; m <<= 1) gtot += __shfl_xor(gtot, m);
    int scan = eqloc;
#pragma unroll
    for (int d = 1; d < 64; d <<= 1) {
        int o = __shfl_up(scan, d);
        if (lane >= d) scan += o;
    }
    int run = scan - eqloc;
    const int quota = k - gtot;

    unsigned short m16[16];
#pragma unroll
    for (int j = 0; j < 16; ++j) {
        bool one;
        if (u[j] > p) one = true;
        else if (u[j] == p) { one = (run < quota); ++run; }
        else one = false;
        m16[j] = one ? (unsigned short)0x3F80 : (unsigned short)0;
    }
    u16x8* dst = (u16x8*)(Mout + (size_t)row * Q_ + lane * 16);
    dst[0] = *(u16x8*)&m16[0];
    dst[1] = *(u16x8*)&m16[8];
}

extern "C" void kernel_launch(void* const* d_in, const int* in_sizes, int n_in,
                              void* d_out, int out_size, void* d_ws, size_t ws_size,
                              hipStream_t stream) {
    const float* x  = (const float*)d_in[0];
    const float* W1 = (const float*)d_in[1];   // [2Q, Q]
    const float* W2 = (const float*)d_in[2];   // [Q, 2Q]
    const float* W3 = (const float*)d_in[3];   // [Q, Q]
    const float* Wc = (const float*)d_in[4];   // [E, Q]
    float* out = (float*)d_out;

    char* ws = (char*)d_ws;
    unsigned short* H1_0 = (unsigned short*)ws;                         // [B,2Q] bf16 hi
    unsigned short* H1_1 = (unsigned short*)(ws + ((size_t)128 << 20)); // [B,2Q] bf16 lo
    float*          SC   = (float*)ws;                                  // scores (aliases H1_0)
    unsigned short* MASKB= (unsigned short*)(ws + ((size_t)128 << 20)); // mask bf16
    int* KV    = (int*)(ws + ((size_t)256 << 20));
    int* FLAGS = KV + B_;
    int* CNT   = FLAGS + B_;
    unsigned short* H2_0 = (unsigned short*)d_out;                      // [B,Q] bf16 hi
    unsigned short* H2_1 = (unsigned short*)d_out + (size_t)B_ * Q_;    // [B,Q] bf16 lo
    float* H1F = (float*)ws;                                            // rescore [n,2Q]
    float* H2F = (float*)(ws + ((size_t)128 << 20));                    // [n,Q]
    float* SCF = (float*)(ws + ((size_t)192 << 20));                    // [n,Q]

    // weight-plane region (fast path only): past the 256MB + KV block
    char* WP = ws + ((size_t)256 << 20) + ((size_t)512 << 10);
    unsigned short* W1h = (unsigned short*)WP;                 // 4MB
    unsigned short* W1l = W1h + (size_t)2 * Q_ * Q_;           // 4MB
    unsigned short* W2h = W1l + (size_t)2 * Q_ * Q_;           // 4MB
    unsigned short* W2l = W2h + (size_t)2 * Q_ * Q_;           // 4MB
    unsigned short* W3h = W2l + (size_t)2 * Q_ * Q_;           // 2MB
    unsigned short* W3l = W3h + (size_t)Q_ * Q_;               // 2MB
    unsigned short* Wch = W3l + (size_t)Q_ * Q_;               // 2MB
    const size_t NEEDED = ((size_t)256 << 20) + ((size_t)512 << 10) + ((size_t)22 << 20);

    hipMemsetAsync(CNT, 0, sizeof(int), stream);
    dim3 blk(256);

    if (ws_size >= NEEDED) {
        // x planes staged in d_out (dead once layer-2 overwrites with H2 planes)
        unsigned short* Xh = (unsigned short*)d_out;
        unsigned short* Xl = Xh + (size_t)B_ * Q_;
        split_planes_k<<<dim3(2048), blk, 0, stream>>>(x,  Xh,  Xl,  B_ * Q_ / 8);
        split_planes_k<<<dim3(512),  blk, 0, stream>>>(W1, W1h, W1l, 2 * Q_ * Q_ / 8);
        split_planes_k<<<dim3(512),  blk, 0, stream>>>(W2, W2h, W2l, 2 * Q_ * Q_ / 8);
        split_planes_k<<<dim3(512),  blk, 0, stream>>>(W3, W3h, W3l, Q_ * Q_ / 8);
        cvt_plane_k   <<<dim3(512),  blk, 0, stream>>>(Wc, Wch, E_ * Q_ / 8);
        // h1 = relu(x @ W1^T)
        gemm_pp<3, true,  true ><<<dim3((2 * Q_ / 128) * (B_ / 128)), blk, 0, stream>>>(
            Xh, Xl, W1h, W1l, H1_0, H1_1, B_, 2 * Q_, Q_);
        // h2 = relu(h1 @ W2^T) -> planes in d_out (x planes now dead)
        gemm_pp<3, true,  true ><<<dim3((Q_ / 128) * (B_ / 128)), blk, 0, stream>>>(
            H1_0, H1_1, W2h, W2l, H2_0, H2_1, B_, Q_, 2 * Q_);
        // scores = h2 @ W3^T
        gemm_pp<3, false, false><<<dim3((Q_ / 128) * (B_ / 128)), blk, 0, stream>>>(
            H2_0, H2_1, W3h, W3l, SC, nullptr, B_, Q_, Q_);
        row_argmax_flag<<<dim3(B_ / 4), blk, 0, stream>>>(SC, KV, FLAGS, CNT);
        rescore_gemm<true,  true ><<<dim3(2048), blk, 0, stream>>>(x,   W1, H1F, FLAGS, CNT, Q_,     2 * Q_);
        rescore_gemm<false, true ><<<dim3(1024), blk, 0, stream>>>(H1F, W2, H2F, FLAGS, CNT, 2 * Q_, Q_);
        rescore_gemm<false, false><<<dim3(1024), blk, 0, stream>>>(H2F, W3, SCF, FLAGS, CNT, Q_,     Q_);
        rescore_argmax<<<dim3(64), blk, 0, stream>>>(SCF, FLAGS, CNT, KV);
        topk_mask_radix<<<dim3(B_ / 4), blk, 0, stream>>>(x, KV, MASKB);
        // out = mask @ Wc^T (plain bf16 MFMA)
        gemm_pp<1, false, false><<<dim3((E_ / 128) * (B_ / 128)), blk, 0, stream>>>(
            MASKB, nullptr, Wch, nullptr, out, nullptr, B_, E_, Q_);
    } else {
        // fallback: round-4 path (in-kernel split)
        gemm3p<3, true,  true,  true ><<<dim3(2 * Q_ / 128, B_ / 128), blk, 0, stream>>>(
            x, nullptr, W1, H1_0, H1_1, B_, 2 * Q_, Q_);
        gemm3p<3, false, true,  true ><<<dim3(Q_ / 128, B_ / 128), blk, 0, stream>>>(
            H1_0, H1_1, W2, H2_0, H2_1, B_, Q_, 2 * Q_);
        gemm3p<3, false, false, false><<<dim3(Q_ / 128, B_ / 128), blk, 0, stream>>>(
            H2_0, H2_1, W3, SC, nullptr, B_, Q_, Q_);
        row_argmax_flag<<<dim3(B_ / 4), blk, 0, stream>>>(SC, KV, FLAGS, CNT);
        rescore_gemm<true,  true ><<<dim3(2048), blk, 0, stream>>>(x,   W1, H1F, FLAGS, CNT, Q_,     2 * Q_);
        rescore_gemm<false, true ><<<dim3(1024), blk, 0, stream>>>(H1F, W2, H2F, FLAGS, CNT, 2 * Q_, Q_);
        rescore_gemm<false, false><<<dim3(1024), blk, 0, stream>>>(H2F, W3, SCF, FLAGS, CNT, Q_,     Q_);
        rescore_argmax<<<dim3(64), blk, 0, stream>>>(SCF, FLAGS, CNT, KV);
        topk_mask_radix<<<dim3(B_ / 4), blk, 0, stream>>>(x, KV, MASKB);
        gemm3p<1, false, false, false><<<dim3(E_ / 128, B_ / 128), blk, 0, stream>>>(
            MASKB, nullptr, Wc, out, nullptr, B_, E_, Q_);
    }
}